// Round 10
// baseline (317.164 us; speedup 1.0000x reference)
//
#include <hip/hip_runtime.h>
#include <hip/hip_bf16.h>

#define N_NODES 50000
#define N_EDGES 800000
#define N_GRAPHS 64
#define LSTR 136
#define NP 50016

typedef __attribute__((ext_vector_type(4))) short s4v;
typedef __attribute__((ext_vector_type(8))) short s8v;
typedef __attribute__((ext_vector_type(16))) float f16v;

struct HL { short hi, lo; };

__device__ inline HL bsplit(float f) {
    HL r;
    unsigned u = __float_as_uint(f);
    unsigned rh = (u + 0x7FFFu + ((u >> 16) & 1u)) >> 16;
    r.hi = (short)rh;
    float fh = __uint_as_float(rh << 16);
    float fl = f - fh;
    unsigned u2 = __float_as_uint(fl);
    unsigned rl = (u2 + 0x7FFFu + ((u2 >> 16) & 1u)) >> 16;
    r.lo = (short)rl;
    return r;
}

__device__ inline unsigned short f2bf(float f) {
    unsigned u = __float_as_uint(f);
    return (unsigned short)((u + 0x7FFFu + ((u >> 16) & 1u)) >> 16);
}

__device__ inline float bflo(unsigned u) { return __uint_as_float(u << 16); }
__device__ inline float bfhi(unsigned u) { return __uint_as_float(u & 0xFFFF0000u); }

// ---------------- CSR scan kernels (8-way split counters) ----------------
// scan_a also RE-ZEROES cnt8 so the fill pass can regenerate ranks by atomicAdd.
__global__ __launch_bounds__(512) void k_scan_a(int* __restrict__ cnt8,
                                                int* __restrict__ rowptr,
                                                int* __restrict__ bsum,
                                                float* __restrict__ dinv,
                                                int* __restrict__ base8, int n) {
    __shared__ int s[512];
    int t = threadIdx.x;
    int i = blockIdx.x * 512 + t;
    int deg = 0;
    if (i < n) {
        int acc = 0;
        #pragma unroll
        for (int p = 0; p < 8; ++p) {
            int c = cnt8[p * NP + i];
            base8[p * NP + i] = acc;
            cnt8[p * NP + i] = 0;            // reset for fill's second atomic pass
            acc += c;
        }
        deg = acc;
        dinv[i] = rsqrtf((float)(deg + 1));
    }
    int pv = (deg + 7) & ~7;
    s[t] = pv;
    __syncthreads();
    for (int d = 1; d < 512; d <<= 1) {
        int x = (t >= d) ? s[t - d] : 0;
        __syncthreads();
        s[t] += x;
        __syncthreads();
    }
    if (i < n) rowptr[i] = s[t] - pv;
    if (t == 511) bsum[blockIdx.x] = s[511];
}

__global__ __launch_bounds__(512) void k_scan_c(int* __restrict__ rowptr,
                                                const int* __restrict__ bsum,
                                                int n, int nb) {
    __shared__ int sb[128];
    int t = threadIdx.x;
    if (t < 128) sb[t] = (t < nb) ? bsum[t] : 0;
    __syncthreads();
    for (int d = 1; d < 128; d <<= 1) {
        int x = 0;
        if (t < 128 && t >= d) x = sb[t - d];
        __syncthreads();
        if (t < 128) sb[t] += x;
        __syncthreads();
    }
    int add = (blockIdx.x > 0) ? sb[blockIdx.x - 1] : 0;
    int i = blockIdx.x * 512 + t;
    if (i < n) rowptr[i] += add;
    if (i == 0) rowptr[n] = sb[nb - 1];
}

// ---- prep combo. CNT8 must be zeroed (memsetAsync) BEFORE this kernel.
// b 0..63: qq | 64..199: wsplit | 200..480: colA pad | 481: dummy Hs rows | 482..: hist
// Hist: count-only (no rank store). Partial id p = (e>>9)&7 is a pure function of e,
// so the fill pass can regenerate in-range ranks with its own atomicAdd pass.
__global__ __launch_bounds__(512) void k_prep(const float* __restrict__ qe,
                                              const float* __restrict__ fc0w,
                                              const float* __restrict__ fc0b,
                                              const float* __restrict__ fc1w,
                                              const float* __restrict__ fc1b,
                                              const float* __restrict__ W0,
                                              const float* __restrict__ W1,
                                              const float* __restrict__ W2,
                                              const float* __restrict__ fc2w,
                                              const int* __restrict__ ei,
                                              int* __restrict__ cnt8,
                                              short* __restrict__ WH,
                                              short* __restrict__ WL,
                                              unsigned* __restrict__ Hsd,
                                              unsigned short* __restrict__ colA,
                                              float* __restrict__ qq, int E) {
    int b = blockIdx.x, tid = threadIdx.x;
    if (b >= 482) {                       // histogram (CNT8 pre-zeroed)
        int e = (b - 482) * 512 + tid;
        if (e < E) {
            int p = (e >> 9) & 7;
            atomicAdd(&cnt8[p * NP + ei[E + e]], 1);
        }
        return;
    }
    if (b == 481) {                       // dummy rows: HS and HS2 (contiguous regions)
        if (tid < 64) Hsd[(unsigned)N_NODES * 64u + tid] = 0u;
        if (tid >= 64 && tid < 128) Hsd[100001u * 64u + (unsigned)(tid - 64)] = 0u;
        return;
    }
    if (b >= 200) {                       // colA pad prefill: 1,150,016 ushorts as uint4
        int idx = (b - 200) * 512 + tid;
        if (idx < 143752) {
            uint4 p;
            p.x = p.y = p.z = p.w = 0xC350C350u;   // 50000 | 50000<<16
            ((uint4*)colA)[idx] = p;
        }
        return;
    }
    if (b >= 64) {                        // weight split: 136 blocks x 512 = 69632 exact
        int i = (b - 64) * 512 + tid;
        float val;
        int dst;
        if (i < 65536) {
            int mat = i >> 14, off = i & 16383;
            int k = off >> 7, n = off & 127;
            const float* src = (mat == 0) ? W0 : (mat == 1) ? W1 : (mat == 2) ? W2 : fc1w;
            val = src[k * 128 + n];
            dst = mat * 16384 + n * 128 + k;
        } else {
            int off = i - 65536;
            int k = off >> 5, n = off & 31;
            val = fc2w[k * 32 + n];
            dst = 65536 + n * 128 + k;
        }
        HL r = bsplit(val);
        WH[dst] = r.hi;
        WL[dst] = r.lo;
        return;
    }
    // question path, graph g = b
    __shared__ float qs[768];
    __shared__ float red[512];
    __shared__ float ql[128];
    const float* fc1bot = fc1w + 128 * 128;
    int g = b;
    for (int i = tid; i < 768; i += 512) qs[i] = qe[g * 768 + i];
    __syncthreads();
    int j = tid & 127, sl = tid >> 7;
    int kb = sl * 192;
    float a0 = 0, a1 = 0, a2 = 0, a3 = 0;
    for (int k = 0; k < 192; k += 4) {
        a0 += qs[kb + k + 0] * fc0w[(kb + k + 0) * 128 + j];
        a1 += qs[kb + k + 1] * fc0w[(kb + k + 1) * 128 + j];
        a2 += qs[kb + k + 2] * fc0w[(kb + k + 2) * 128 + j];
        a3 += qs[kb + k + 3] * fc0w[(kb + k + 3) * 128 + j];
    }
    red[tid] = (a0 + a1) + (a2 + a3);
    __syncthreads();
    if (tid < 128)
        ql[tid] = fmaxf(((red[tid] + red[tid + 128]) + (red[tid + 256] + red[tid + 384]))
                        + fc0b[tid], 0.f);
    __syncthreads();
    kb = sl * 32;
    float b0 = 0, b1 = 0;
    for (int k = 0; k < 32; k += 2) {
        b0 += ql[kb + k + 0] * fc1bot[(kb + k + 0) * 128 + j];
        b1 += ql[kb + k + 1] * fc1bot[(kb + k + 1) * 128 + j];
    }
    red[tid] = b0 + b1;
    __syncthreads();
    if (tid < 128)
        qq[g * 128 + tid] = ((red[tid] + red[tid + 128]) + (red[tid + 256] + red[tid + 384]))
                            + fc1b[tid];
}

// ---------------- merged layer-1 GEMM + CSR fill (rank regenerated by atomics) ------
__global__ __launch_bounds__(128) void k_fg(const float* __restrict__ A32,
                                            const short* __restrict__ WTh,
                                            const short* __restrict__ WTl,
                                            const float* __restrict__ dinv,
                                            unsigned short* __restrict__ oHs,
                                            const int* __restrict__ ei,
                                            const int* __restrict__ rowptr,
                                            int* __restrict__ cnt8,
                                            const int* __restrict__ base8,
                                            unsigned short* __restrict__ colA,
                                            int nrows, int E, int GG) {
    const int tid = threadIdx.x;
    if (blockIdx.x >= GG) {                     // CSR fill part
        int e = (blockIdx.x - GG) * 128 + tid;
        if (e < E) {
            int dst = ei[E + e];
            int p = (e >> 9) & 7;               // SAME e->p map as hist => r in range
            int r = atomicAdd(&cnt8[p * NP + dst], 1);
            colA[rowptr[dst] + base8[p * NP + dst] + r] = (unsigned short)ei[e];
        }
        return;
    }
    __shared__ short Ah[32 * LSTR];
    const int row0 = blockIdx.x * 32;

    #pragma unroll
    for (int i = 0; i < 8; ++i) {
        int u = i * 128 + tid;
        int r = u >> 5, c4 = u & 31;
        int gr = row0 + r;
        float4 v = make_float4(0.f, 0.f, 0.f, 0.f);
        if (gr < nrows) v = ((const float4*)A32)[(size_t)gr * 32 + c4];
        s4v h4 = {(short)f2bf(v.x), (short)f2bf(v.y), (short)f2bf(v.z), (short)f2bf(v.w)};
        *(s4v*)&Ah[r * LSTR + c4 * 4] = h4;
    }
    __syncthreads();

    const int wv = tid >> 6, lane = tid & 63;
    const int m = lane & 31, half = lane >> 5;
    const int c0 = wv * 64 + m;
    f16v acc0 = {0.f}, acc1 = {0.f};
    #pragma unroll
    for (int ks = 0; ks < 8; ++ks) {
        int ko = ks * 16 + half * 8;
        s8v ah  = *(const s8v*)&Ah[m * LSTR + ko];
        s8v bh0 = *(const s8v*)&WTh[(size_t)c0 * 128 + ko];
        s8v bl0 = *(const s8v*)&WTl[(size_t)c0 * 128 + ko];
        s8v bh1 = *(const s8v*)&WTh[(size_t)(c0 + 32) * 128 + ko];
        s8v bl1 = *(const s8v*)&WTl[(size_t)(c0 + 32) * 128 + ko];
        acc0 = __builtin_amdgcn_mfma_f32_32x32x16_bf16(ah, bh0, acc0, 0, 0, 0);
        acc0 = __builtin_amdgcn_mfma_f32_32x32x16_bf16(ah, bl0, acc0, 0, 0, 0);
        acc1 = __builtin_amdgcn_mfma_f32_32x32x16_bf16(ah, bh1, acc1, 0, 0, 0);
        acc1 = __builtin_amdgcn_mfma_f32_32x32x16_bf16(ah, bl1, acc1, 0, 0, 0);
    }

    #pragma unroll
    for (int reg = 0; reg < 16; ++reg) {
        int rl = (reg & 3) + 8 * (reg >> 2) + 4 * half;
        int gr = row0 + rl;
        if (gr >= nrows) continue;
        float sc = dinv[gr];
        __builtin_nontemporal_store(f2bf(acc0[reg] * sc), &oHs[(size_t)gr * 128 + c0]);
        __builtin_nontemporal_store(f2bf(acc1[reg] * sc), &oHs[(size_t)gr * 128 + c0 + 32]);
    }
}

// ---------------- fused gather + GEMM, 256 thr (4 waves), 8 nodes/wave ----------------
// R6 gather structure + R7 nontemporal epilogue stores (best-known combo).
template <int FC>
__global__ __launch_bounds__(256, 7) void k_gg(const unsigned* __restrict__ Hs,
                                               const int* __restrict__ rowptr,
                                               const unsigned short* __restrict__ colA,
                                               const float* __restrict__ dinv,
                                               const float* __restrict__ bias,
                                               const short* __restrict__ WTh,
                                               const short* __restrict__ WTl,
                                               const short* __restrict__ W2h,
                                               const short* __restrict__ W2l,
                                               const float* __restrict__ qq,
                                               const int* __restrict__ batch,
                                               const float* __restrict__ fc2b,
                                               unsigned short* __restrict__ oHs,
                                               float* __restrict__ out,
                                               int n) {
    __shared__ short SM[(FC ? 64 : 32) * LSTR];
    short* Ah = SM;
    const int tid = threadIdx.x;
    const int row0 = blockIdx.x * 32;
    const int wv = tid >> 6, l = tid & 63;
    const int m = l & 31, half = l >> 5;
    const int il = l & 15;
    const unsigned ilo = (unsigned)(il * 4);
    const unsigned shq = (l & 16) ? 16u : 0u;
    const bool qhi = (l & 32) != 0;
    const bool q0 = (l < 16);

    // wave-cooperative rowptr + dinv prefetch (lanes 0..8 hold the 9 rowptrs)
    int pidx = row0 + wv * 8 + l;
    if (pidx > N_NODES) pidx = N_NODES;
    const int rp = rowptr[pidx];
    const int dvu = (int)__float_as_uint(dinv[pidx < N_NODES ? pidx : N_NODES - 1]);

    const float4 bA = ((const float4*)bias)[il * 2];
    const float4 bB = ((const float4*)bias)[il * 2 + 1];

    int node = row0 + wv * 8;
    int e0 = __builtin_amdgcn_readfirstlane(__builtin_amdgcn_readlane(rp, 0));
    int e1 = __builtin_amdgcn_readfirstlane(__builtin_amdgcn_readlane(rp, 1));
    bool alive = node < n;
    bool act = alive && (e0 < e1);
    uint4 cwA = {0, 0, 0, 0}, sf = {0, 0, 0, 0};
    if (alive) sf = *(const uint4*)(Hs + (unsigned)node * 64u + ilo);
    if (act)   cwA = *(const uint4*)(colA + e0);

    for (int i = 0; i < 8; ++i) {
        float a0 = 0, a1 = 0, a2 = 0, a3 = 0, a4 = 0, a5 = 0, a6 = 0, a7 = 0;
        float c0f = 0, c1f = 0, c2f = 0, c3f = 0, c4f = 0, c5f = 0, c6f = 0, c7f = 0;
        if (act) {
            const int ng = (e1 - e0) >> 3;
            uint4 cwB = *(const uint4*)(colA + e0 + ((ng > 1) ? 8 : 0));
            int g = 0;
            while (g + 2 <= ng) {
                // prefetch quads g+2, g+3 (clamped dups on tail, never consumed wrongly)
                uint4 nA = *(const uint4*)(colA + e0 + ((g + 2 < ng) ? (g + 2) * 8 : 0));
                uint4 nB = *(const uint4*)(colA + e0 + ((g + 3 < ng) ? (g + 3) * 8 : 0));
                // 4 row-gathers in flight (16 edges)
                unsigned wAa = qhi ? cwA.y : cwA.x;
                unsigned wAb = qhi ? cwA.w : cwA.z;
                unsigned wBa = qhi ? cwB.y : cwB.x;
                unsigned wBb = qhi ? cwB.w : cwB.z;
                uint4 va = *(const uint4*)(Hs + ((wAa >> shq) & 0xFFFFu) * 64u + ilo);
                uint4 vb = *(const uint4*)(Hs + ((wAb >> shq) & 0xFFFFu) * 64u + ilo);
                uint4 vc = *(const uint4*)(Hs + ((wBa >> shq) & 0xFFFFu) * 64u + ilo);
                uint4 vd = *(const uint4*)(Hs + ((wBb >> shq) & 0xFFFFu) * 64u + ilo);
                a0 += bflo(va.x); a1 += bfhi(va.x);
                a2 += bflo(va.y); a3 += bfhi(va.y);
                a4 += bflo(va.z); a5 += bfhi(va.z);
                a6 += bflo(va.w); a7 += bfhi(va.w);
                c0f += bflo(vb.x); c1f += bfhi(vb.x);
                c2f += bflo(vb.y); c3f += bfhi(vb.y);
                c4f += bflo(vb.z); c5f += bfhi(vb.z);
                c6f += bflo(vb.w); c7f += bfhi(vb.w);
                a0 += bflo(vc.x); a1 += bfhi(vc.x);
                a2 += bflo(vc.y); a3 += bfhi(vc.y);
                a4 += bflo(vc.z); a5 += bfhi(vc.z);
                a6 += bflo(vc.w); a7 += bfhi(vc.w);
                c0f += bflo(vd.x); c1f += bfhi(vd.x);
                c2f += bflo(vd.y); c3f += bfhi(vd.y);
                c4f += bflo(vd.z); c5f += bfhi(vd.z);
                c6f += bflo(vd.w); c7f += bfhi(vd.w);
                cwA = nA; cwB = nB; g += 2;
            }
            if (g < ng) {                     // odd tail group, indices in cwA
                unsigned wAa = qhi ? cwA.y : cwA.x;
                unsigned wAb = qhi ? cwA.w : cwA.z;
                uint4 va = *(const uint4*)(Hs + ((wAa >> shq) & 0xFFFFu) * 64u + ilo);
                uint4 vb = *(const uint4*)(Hs + ((wAb >> shq) & 0xFFFFu) * 64u + ilo);
                a0 += bflo(va.x); a1 += bfhi(va.x);
                a2 += bflo(va.y); a3 += bfhi(va.y);
                a4 += bflo(va.z); a5 += bfhi(va.z);
                a6 += bflo(va.w); a7 += bfhi(va.w);
                c0f += bflo(vb.x); c1f += bfhi(vb.x);
                c2f += bflo(vb.y); c3f += bfhi(vb.y);
                c4f += bflo(vb.z); c5f += bfhi(vb.z);
                c6f += bflo(vb.w); c7f += bfhi(vb.w);
            }
        }
        float s0 = a0 + c0f, s1 = a1 + c1f, s2 = a2 + c2f, s3 = a3 + c3f;
        float s4 = a4 + c4f, s5 = a5 + c5f, s6 = a6 + c6f, s7 = a7 + c7f;

        // prefetch next node (index quad + self row) before the butterfly
        int e0n = e1;
        int e1n = (i < 7) ? __builtin_amdgcn_readfirstlane(__builtin_amdgcn_readlane(rp, i + 2)) : 0;
        int noden = node + 1;
        bool aliven = (i < 7) && (noden < n);
        bool actn = aliven && (e0n < e1n);
        uint4 cwn = {0, 0, 0, 0}, sfn = {0, 0, 0, 0};
        if (aliven) sfn = *(const uint4*)(Hs + (unsigned)noden * 64u + ilo);
        if (actn)   cwn = *(const uint4*)(colA + e0n);

        const int r = wv * 8 + i;
        if (alive) {
            s0 += __shfl_xor(s0, 16); s1 += __shfl_xor(s1, 16);
            s2 += __shfl_xor(s2, 16); s3 += __shfl_xor(s3, 16);
            s4 += __shfl_xor(s4, 16); s5 += __shfl_xor(s5, 16);
            s6 += __shfl_xor(s6, 16); s7 += __shfl_xor(s7, 16);
            s0 += __shfl_xor(s0, 32); s1 += __shfl_xor(s1, 32);
            s2 += __shfl_xor(s2, 32); s3 += __shfl_xor(s3, 32);
            s4 += __shfl_xor(s4, 32); s5 += __shfl_xor(s5, 32);
            s6 += __shfl_xor(s6, 32); s7 += __shfl_xor(s7, 32);
            float di = __uint_as_float((unsigned)__builtin_amdgcn_readlane(dvu, i));
            float o0 = fmaxf((s0 + bflo(sf.x)) * di + bA.x, 0.f);
            float o1 = fmaxf((s1 + bfhi(sf.x)) * di + bA.y, 0.f);
            float o2 = fmaxf((s2 + bflo(sf.y)) * di + bA.z, 0.f);
            float o3 = fmaxf((s3 + bfhi(sf.y)) * di + bA.w, 0.f);
            float o4 = fmaxf((s4 + bflo(sf.z)) * di + bB.x, 0.f);
            float o5 = fmaxf((s5 + bfhi(sf.z)) * di + bB.y, 0.f);
            float o6 = fmaxf((s6 + bflo(sf.w)) * di + bB.z, 0.f);
            float o7 = fmaxf((s7 + bfhi(sf.w)) * di + bB.w, 0.f);
            if (q0) {
                uint4 pk;
                pk.x = (unsigned)f2bf(o0) | ((unsigned)f2bf(o1) << 16);
                pk.y = (unsigned)f2bf(o2) | ((unsigned)f2bf(o3) << 16);
                pk.z = (unsigned)f2bf(o4) | ((unsigned)f2bf(o5) << 16);
                pk.w = (unsigned)f2bf(o6) | ((unsigned)f2bf(o7) << 16);
                *(uint4*)&Ah[r * LSTR + il * 8] = pk;
            }
        } else if (q0) {
            uint4 z = {0, 0, 0, 0};
            *(uint4*)&Ah[r * LSTR + il * 8] = z;
        }
        e0 = e0n; e1 = e1n; cwA = cwn; sf = sfn;
        act = actn; alive = aliven; node = noden;
    }
    __syncthreads();

    const int c0 = wv * 32 + m;                 // all 4 waves: one 32-col block each
    f16v acc = {0.f};
    #pragma unroll
    for (int ks = 0; ks < 8; ++ks) {
        int ko = ks * 16 + half * 8;
        s8v ah = *(const s8v*)&Ah[m * LSTR + ko];
        s8v bh = *(const s8v*)&WTh[(size_t)c0 * 128 + ko];
        s8v bl = *(const s8v*)&WTl[(size_t)c0 * 128 + ko];
        acc = __builtin_amdgcn_mfma_f32_32x32x16_bf16(ah, bh, acc, 0, 0, 0);
        acc = __builtin_amdgcn_mfma_f32_32x32x16_bf16(ah, bl, acc, 0, 0, 0);
    }

    if (FC == 0) {
        #pragma unroll
        for (int reg = 0; reg < 16; ++reg) {
            int rl = (reg & 3) + 8 * (reg >> 2) + 4 * half;
            int gr = row0 + rl;
            if (gr >= n) continue;
            __builtin_nontemporal_store(f2bf(acc[reg] * dinv[gr]),
                                        &oHs[(size_t)gr * 128 + c0]);
        }
    } else {
        short* Pl = SM + 32 * LSTR;
        __syncthreads();                        // all waves done reading Ah
        #pragma unroll
        for (int reg = 0; reg < 16; ++reg) {    // relu(+qq), split into Ah/Pl planes
            int rl = (reg & 3) + 8 * (reg >> 2) + 4 * half;
            int gr = row0 + rl;
            int g = (gr < n) ? batch[gr] : 0;
            float v = fmaxf(acc[reg] + qq[(size_t)g * 128 + c0], 0.f);
            HL p = bsplit(v);
            Ah[rl * LSTR + c0] = p.hi;
            Pl[rl * LSTR + c0] = p.lo;
        }
        __syncthreads();
        f16v acc2 = {0.f};                      // fc2, split-K across the 4 waves
        #pragma unroll
        for (int ks = 0; ks < 2; ++ks) {
            int ko = wv * 32 + ks * 16 + half * 8;
            s8v ah = *(const s8v*)&Ah[m * LSTR + ko];
            s8v al = *(const s8v*)&Pl[m * LSTR + ko];
            s8v bh = *(const s8v*)&W2h[(size_t)m * 128 + ko];
            s8v bl = *(const s8v*)&W2l[(size_t)m * 128 + ko];
            acc2 = __builtin_amdgcn_mfma_f32_32x32x16_bf16(ah, bh, acc2, 0, 0, 0);
            acc2 = __builtin_amdgcn_mfma_f32_32x32x16_bf16(ah, bl, acc2, 0, 0, 0);
            acc2 = __builtin_amdgcn_mfma_f32_32x32x16_bf16(al, bh, acc2, 0, 0, 0);
        }
        __syncthreads();                        // alias guard: Ah/Pl reads all retired
        float* red = (float*)SM;                // 12672 B <= 17408 B (Ah+Pl)
        if (wv > 0) {
            #pragma unroll
            for (int reg = 0; reg < 16; ++reg) {
                int rl = (reg & 3) + 8 * (reg >> 2) + 4 * half;
                red[(wv - 1) * 1056 + rl * 33 + m] = acc2[reg];
            }
        }
        __syncthreads();
        if (wv == 0) {
            #pragma unroll
            for (int reg = 0; reg < 16; ++reg) {
                int rl = (reg & 3) + 8 * (reg >> 2) + 4 * half;
                int gr = row0 + rl;
                if (gr < n) {
                    float v = acc2[reg]
                        + (red[rl * 33 + m] + red[1056 + rl * 33 + m])
                        + red[2112 + rl * 33 + m] + fc2b[m];
                    __builtin_nontemporal_store(v, &out[(size_t)gr * 32 + m]);
                }
            }
        }
    }
}

// ---------------- launch ----------------

extern "C" void kernel_launch(void* const* d_in, const int* in_sizes, int n_in,
                              void* d_out, int out_size, void* d_ws, size_t ws_size,
                              hipStream_t stream) {
    const float* x    = (const float*)d_in[0];
    const int*   ei   = (const int*)d_in[1];
    const int*   batch= (const int*)d_in[2];
    const float* qe   = (const float*)d_in[3];
    const float* W0   = (const float*)d_in[4];
    const float* b0   = (const float*)d_in[5];
    const float* W1   = (const float*)d_in[6];
    const float* b1   = (const float*)d_in[7];
    const float* W2   = (const float*)d_in[8];
    const float* b2   = (const float*)d_in[9];
    const float* fc0w = (const float*)d_in[10];
    const float* fc0b = (const float*)d_in[11];
    const float* fc1w = (const float*)d_in[12];
    const float* fc1b = (const float*)d_in[13];
    const float* fc2w = (const float*)d_in[14];
    const float* fc2b = (const float*)d_in[15];
    float* out = (float*)d_out;

    float* WS = (float*)d_ws;
    unsigned short* HS  = (unsigned short*)WS;                // bf16 [50001,128]
    unsigned short* HS2 = (unsigned short*)(WS + 3200064);    // bf16 [50001,128]
    float* DINV = WS + 6400128;              // [50016]
    float* QQ   = WS + 6450144;              // [8192]
    int*   ROWPTR = (int*)(WS + 6508352);    // [50016]
    unsigned short* COL = (unsigned short*)(WS + 7358368);    // [1150016] ushort
    int*   BSUM = (int*)(WS + 7933376);      // [128]
    short* WTH  = (short*)(WS + 7933504);    // [69632]
    short* WTL  = WTH + 69632;               // [69632]
    // CNT8/BASE8 overlay HS2's row space (dead until first k_gg writes it)
    int*   CNT8  = (int*)HS2;                // [8][50016]
    int*   BASE8 = CNT8 + 8 * NP;            // [8][50016]

    const int N = N_NODES, E = N_EDGES;
    const int sb = (N + 511) / 512;          // 98
    const int gg = (N + 31) / 32;            // 1563
    const int histb = (E + 511) / 512;       // 1563
    const int fillb = (E + 127) / 128;       // 6250

    // ---- CNT8 zero, then prep (qq + wsplit + colA pad + dummy rows + hist) ----
    (void)hipMemsetAsync(CNT8, 0, 8 * NP * sizeof(int), stream);
    k_prep<<<482 + histb, 512, 0, stream>>>(qe, fc0w, fc0b, fc1w, fc1b,
                                            W0, W1, W2, fc2w, ei, CNT8,
                                            WTH, WTL, (unsigned*)HS, COL, QQ, E);
    // ---- scan (scan_a also re-zeroes CNT8 for the fill pass) ----
    k_scan_a<<<sb, 512, 0, stream>>>(CNT8, ROWPTR, BSUM, DINV, BASE8, N);
    k_scan_c<<<sb, 512, 0, stream>>>(ROWPTR, BSUM, N, sb);
    // ---- layer-1 GEMM (x@W0 -> HS) + CSR fill (rank regenerated), merged ----
    k_fg<<<gg + fillb, 128, 0, stream>>>(x, WTH, WTL, DINV, HS,
                                         ei, ROWPTR, CNT8, BASE8, COL, N, E, gg);
    // ---- layer 2: gather(HS,b0) + @W1 -> HS2 ----
    k_gg<0><<<gg, 256, 0, stream>>>((const unsigned*)HS, ROWPTR, COL, DINV, b0,
                                    WTH + 16384, WTL + 16384, nullptr, nullptr,
                                    nullptr, nullptr, nullptr, HS2, nullptr, N);
    // ---- layer 3: gather(HS2,b1) + @W2 -> HS ----
    k_gg<0><<<gg, 256, 0, stream>>>((const unsigned*)HS2, ROWPTR, COL, DINV, b1,
                                    WTH + 32768, WTL + 32768, nullptr, nullptr,
                                    nullptr, nullptr, nullptr, HS, nullptr, N);
    // ---- final: gather(HS,b2) + fc1(+qq,relu) + fc2 -> d_out ----
    k_gg<1><<<gg, 256, 0, stream>>>((const unsigned*)HS, ROWPTR, COL, DINV, b2,
                                    WTH + 49152, WTL + 49152, WTH + 65536, WTL + 65536,
                                    QQ, batch, fc2b, nullptr, out, N);
}

// Round 11
// 304.504 us; speedup vs baseline: 1.0416x; 1.0416x over previous
//
#include <hip/hip_runtime.h>
#include <hip/hip_bf16.h>

#define N_NODES 50000
#define N_EDGES 800000
#define N_GRAPHS 64
#define LSTR 136
#define NP 50016

typedef __attribute__((ext_vector_type(4))) short s4v;
typedef __attribute__((ext_vector_type(8))) short s8v;
typedef __attribute__((ext_vector_type(16))) float f16v;

struct HL { short hi, lo; };

__device__ inline HL bsplit(float f) {
    HL r;
    unsigned u = __float_as_uint(f);
    unsigned rh = (u + 0x7FFFu + ((u >> 16) & 1u)) >> 16;
    r.hi = (short)rh;
    float fh = __uint_as_float(rh << 16);
    float fl = f - fh;
    unsigned u2 = __float_as_uint(fl);
    unsigned rl = (u2 + 0x7FFFu + ((u2 >> 16) & 1u)) >> 16;
    r.lo = (short)rl;
    return r;
}

__device__ inline unsigned short f2bf(float f) {
    unsigned u = __float_as_uint(f);
    return (unsigned short)((u + 0x7FFFu + ((u >> 16) & 1u)) >> 16);
}

__device__ inline float bflo(unsigned u) { return __uint_as_float(u << 16); }
__device__ inline float bfhi(unsigned u) { return __uint_as_float(u & 0xFFFF0000u); }

// ---------------- CSR scan kernels (8-way split counters, R6-proven) ----------------

__global__ __launch_bounds__(512) void k_scan_a(const int* __restrict__ cnt8,
                                                int* __restrict__ rowptr,
                                                int* __restrict__ bsum,
                                                float* __restrict__ dinv,
                                                int* __restrict__ base8, int n) {
    __shared__ int s[512];
    int t = threadIdx.x;
    int i = blockIdx.x * 512 + t;
    int deg = 0;
    if (i < n) {
        int b = 0;
        #pragma unroll
        for (int p = 0; p < 8; ++p) {
            int c = cnt8[p * NP + i];
            base8[p * NP + i] = b;
            b += c;
        }
        deg = b;
        dinv[i] = rsqrtf((float)(deg + 1));
    }
    int pv = (deg + 7) & ~7;
    s[t] = pv;
    __syncthreads();
    for (int d = 1; d < 512; d <<= 1) {
        int x = (t >= d) ? s[t - d] : 0;
        __syncthreads();
        s[t] += x;
        __syncthreads();
    }
    if (i < n) rowptr[i] = s[t] - pv;
    if (t == 511) bsum[blockIdx.x] = s[511];
}

__global__ __launch_bounds__(512) void k_scan_c(int* __restrict__ rowptr,
                                                const int* __restrict__ bsum,
                                                int n, int nb) {
    __shared__ int sb[128];
    int t = threadIdx.x;
    if (t < 128) sb[t] = (t < nb) ? bsum[t] : 0;
    __syncthreads();
    for (int d = 1; d < 128; d <<= 1) {
        int x = 0;
        if (t < 128 && t >= d) x = sb[t - d];
        __syncthreads();
        if (t < 128) sb[t] += x;
        __syncthreads();
    }
    int add = (blockIdx.x > 0) ? sb[blockIdx.x - 1] : 0;
    int i = blockIdx.x * 512 + t;
    if (i < n) rowptr[i] += add;
    if (i == 0) rowptr[n] = sb[nb - 1];
}

// ---- prep combo (R6-proven). CNT8 must be zeroed (memsetAsync) BEFORE this kernel.
// b 0..63: qq | 64..199: wsplit | 200..480: colA pad | 481: dummy Hs rows | 482..: hist
// Hist: p = blockIdx&7 ~ XCD id under round-robin dispatch -> XCD-local atomics.
// rank packs (partial id << 24) | sub-rank for the replay fill (NO second atomic pass
// -- R10 proved rank-regeneration causes a cross-XCD atomic storm, WRITE 72.7MB).
__global__ __launch_bounds__(512) void k_prep(const float* __restrict__ qe,
                                              const float* __restrict__ fc0w,
                                              const float* __restrict__ fc0b,
                                              const float* __restrict__ fc1w,
                                              const float* __restrict__ fc1b,
                                              const float* __restrict__ W0,
                                              const float* __restrict__ W1,
                                              const float* __restrict__ W2,
                                              const float* __restrict__ fc2w,
                                              const int* __restrict__ ei,
                                              int* __restrict__ cnt8,
                                              int* __restrict__ rank,
                                              short* __restrict__ WH,
                                              short* __restrict__ WL,
                                              unsigned* __restrict__ Hsd,
                                              unsigned short* __restrict__ colA,
                                              float* __restrict__ qq, int E) {
    int b = blockIdx.x, tid = threadIdx.x;
    if (b >= 482) {                       // histogram + rank (CNT8 pre-zeroed)
        int e = (b - 482) * 512 + tid;
        if (e < E) {
            int dst = ei[E + e];
            int p = b & 7;
            int r = atomicAdd(&cnt8[p * NP + dst], 1);
            rank[e] = (p << 24) | r;
        }
        return;
    }
    if (b == 481) {                       // dummy rows: HS and HS2 (contiguous regions)
        if (tid < 64) Hsd[(unsigned)N_NODES * 64u + tid] = 0u;
        if (tid >= 64 && tid < 128) Hsd[100001u * 64u + (unsigned)(tid - 64)] = 0u;
        return;
    }
    if (b >= 200) {                       // colA pad prefill: 1,150,016 ushorts as uint4
        int idx = (b - 200) * 512 + tid;
        if (idx < 143752) {
            uint4 p;
            p.x = p.y = p.z = p.w = 0xC350C350u;   // 50000 | 50000<<16
            ((uint4*)colA)[idx] = p;
        }
        return;
    }
    if (b >= 64) {                        // weight split: 136 blocks x 512 = 69632 exact
        int i = (b - 64) * 512 + tid;
        float val;
        int dst;
        if (i < 65536) {
            int mat = i >> 14, off = i & 16383;
            int k = off >> 7, n = off & 127;
            const float* src = (mat == 0) ? W0 : (mat == 1) ? W1 : (mat == 2) ? W2 : fc1w;
            val = src[k * 128 + n];
            dst = mat * 16384 + n * 128 + k;
        } else {
            int off = i - 65536;
            int k = off >> 5, n = off & 31;
            val = fc2w[k * 32 + n];
            dst = 65536 + n * 128 + k;
        }
        HL r = bsplit(val);
        WH[dst] = r.hi;
        WL[dst] = r.lo;
        return;
    }
    // question path, graph g = b
    __shared__ float qs[768];
    __shared__ float red[512];
    __shared__ float ql[128];
    const float* fc1bot = fc1w + 128 * 128;
    int g = b;
    for (int i = tid; i < 768; i += 512) qs[i] = qe[g * 768 + i];
    __syncthreads();
    int j = tid & 127, sl = tid >> 7;
    int kb = sl * 192;
    float a0 = 0, a1 = 0, a2 = 0, a3 = 0;
    for (int k = 0; k < 192; k += 4) {
        a0 += qs[kb + k + 0] * fc0w[(kb + k + 0) * 128 + j];
        a1 += qs[kb + k + 1] * fc0w[(kb + k + 1) * 128 + j];
        a2 += qs[kb + k + 2] * fc0w[(kb + k + 2) * 128 + j];
        a3 += qs[kb + k + 3] * fc0w[(kb + k + 3) * 128 + j];
    }
    red[tid] = (a0 + a1) + (a2 + a3);
    __syncthreads();
    if (tid < 128)
        ql[tid] = fmaxf(((red[tid] + red[tid + 128]) + (red[tid + 256] + red[tid + 384]))
                        + fc0b[tid], 0.f);
    __syncthreads();
    kb = sl * 32;
    float b0 = 0, b1 = 0;
    for (int k = 0; k < 32; k += 2) {
        b0 += ql[kb + k + 0] * fc1bot[(kb + k + 0) * 128 + j];
        b1 += ql[kb + k + 1] * fc1bot[(kb + k + 1) * 128 + j];
    }
    red[tid] = b0 + b1;
    __syncthreads();
    if (tid < 128)
        qq[g * 128 + tid] = ((red[tid] + red[tid + 128]) + (red[tid + 256] + red[tid + 384]))
                            + fc1b[tid];
}

// ---------------- merged layer-1 GEMM + CSR fill (RANK replay, R6-proven) ----------
__global__ __launch_bounds__(128) void k_fg(const float* __restrict__ A32,
                                            const short* __restrict__ WTh,
                                            const short* __restrict__ WTl,
                                            const float* __restrict__ dinv,
                                            unsigned short* __restrict__ oHs,
                                            const int* __restrict__ ei,
                                            const int* __restrict__ rowptr,
                                            const int* __restrict__ rank,
                                            const int* __restrict__ base8,
                                            unsigned short* __restrict__ colA,
                                            int nrows, int E, int GG) {
    const int tid = threadIdx.x;
    if (blockIdx.x >= GG) {                     // CSR fill part (no atomics)
        int e = (blockIdx.x - GG) * 128 + tid;
        if (e < E) {
            int dst = ei[E + e];
            int rk = rank[e];
            int p = rk >> 24, r = rk & 0xFFFFFF;
            colA[rowptr[dst] + base8[p * NP + dst] + r] = (unsigned short)ei[e];
        }
        return;
    }
    __shared__ short Ah[32 * LSTR];
    const int row0 = blockIdx.x * 32;

    #pragma unroll
    for (int i = 0; i < 8; ++i) {
        int u = i * 128 + tid;
        int r = u >> 5, c4 = u & 31;
        int gr = row0 + r;
        float4 v = make_float4(0.f, 0.f, 0.f, 0.f);
        if (gr < nrows) v = ((const float4*)A32)[(size_t)gr * 32 + c4];
        s4v h4 = {(short)f2bf(v.x), (short)f2bf(v.y), (short)f2bf(v.z), (short)f2bf(v.w)};
        *(s4v*)&Ah[r * LSTR + c4 * 4] = h4;
    }
    __syncthreads();

    const int wv = tid >> 6, lane = tid & 63;
    const int m = lane & 31, half = lane >> 5;
    const int c0 = wv * 64 + m;
    f16v acc0 = {0.f}, acc1 = {0.f};
    #pragma unroll
    for (int ks = 0; ks < 8; ++ks) {
        int ko = ks * 16 + half * 8;
        s8v ah  = *(const s8v*)&Ah[m * LSTR + ko];
        s8v bh0 = *(const s8v*)&WTh[(size_t)c0 * 128 + ko];
        s8v bl0 = *(const s8v*)&WTl[(size_t)c0 * 128 + ko];
        s8v bh1 = *(const s8v*)&WTh[(size_t)(c0 + 32) * 128 + ko];
        s8v bl1 = *(const s8v*)&WTl[(size_t)(c0 + 32) * 128 + ko];
        acc0 = __builtin_amdgcn_mfma_f32_32x32x16_bf16(ah, bh0, acc0, 0, 0, 0);
        acc0 = __builtin_amdgcn_mfma_f32_32x32x16_bf16(ah, bl0, acc0, 0, 0, 0);
        acc1 = __builtin_amdgcn_mfma_f32_32x32x16_bf16(ah, bh1, acc1, 0, 0, 0);
        acc1 = __builtin_amdgcn_mfma_f32_32x32x16_bf16(ah, bl1, acc1, 0, 0, 0);
    }

    #pragma unroll
    for (int reg = 0; reg < 16; ++reg) {
        int rl = (reg & 3) + 8 * (reg >> 2) + 4 * half;
        int gr = row0 + rl;
        if (gr >= nrows) continue;
        float sc = dinv[gr];
        __builtin_nontemporal_store(f2bf(acc0[reg] * sc), &oHs[(size_t)gr * 128 + c0]);
        __builtin_nontemporal_store(f2bf(acc1[reg] * sc), &oHs[(size_t)gr * 128 + c0 + 32]);
    }
}

// ---------------- fused gather + GEMM, 256 thr (4 waves), 8 nodes/wave ----------------
// R6 gather structure + R7 nontemporal epilogue stores (both individually proven).
template <int FC>
__global__ __launch_bounds__(256, 7) void k_gg(const unsigned* __restrict__ Hs,
                                               const int* __restrict__ rowptr,
                                               const unsigned short* __restrict__ colA,
                                               const float* __restrict__ dinv,
                                               const float* __restrict__ bias,
                                               const short* __restrict__ WTh,
                                               const short* __restrict__ WTl,
                                               const short* __restrict__ W2h,
                                               const short* __restrict__ W2l,
                                               const float* __restrict__ qq,
                                               const int* __restrict__ batch,
                                               const float* __restrict__ fc2b,
                                               unsigned short* __restrict__ oHs,
                                               float* __restrict__ out,
                                               int n) {
    __shared__ short SM[(FC ? 64 : 32) * LSTR];
    short* Ah = SM;
    const int tid = threadIdx.x;
    const int row0 = blockIdx.x * 32;
    const int wv = tid >> 6, l = tid & 63;
    const int m = l & 31, half = l >> 5;
    const int il = l & 15;
    const unsigned ilo = (unsigned)(il * 4);
    const unsigned shq = (l & 16) ? 16u : 0u;
    const bool qhi = (l & 32) != 0;
    const bool q0 = (l < 16);

    // wave-cooperative rowptr + dinv prefetch (lanes 0..8 hold the 9 rowptrs)
    int pidx = row0 + wv * 8 + l;
    if (pidx > N_NODES) pidx = N_NODES;
    const int rp = rowptr[pidx];
    const int dvu = (int)__float_as_uint(dinv[pidx < N_NODES ? pidx : N_NODES - 1]);

    const float4 bA = ((const float4*)bias)[il * 2];
    const float4 bB = ((const float4*)bias)[il * 2 + 1];

    int node = row0 + wv * 8;
    int e0 = __builtin_amdgcn_readfirstlane(__builtin_amdgcn_readlane(rp, 0));
    int e1 = __builtin_amdgcn_readfirstlane(__builtin_amdgcn_readlane(rp, 1));
    bool alive = node < n;
    bool act = alive && (e0 < e1);
    uint4 cwA = {0, 0, 0, 0}, sf = {0, 0, 0, 0};
    if (alive) sf = *(const uint4*)(Hs + (unsigned)node * 64u + ilo);
    if (act)   cwA = *(const uint4*)(colA + e0);

    for (int i = 0; i < 8; ++i) {
        float a0 = 0, a1 = 0, a2 = 0, a3 = 0, a4 = 0, a5 = 0, a6 = 0, a7 = 0;
        float c0f = 0, c1f = 0, c2f = 0, c3f = 0, c4f = 0, c5f = 0, c6f = 0, c7f = 0;
        if (act) {
            const int ng = (e1 - e0) >> 3;
            uint4 cwB = *(const uint4*)(colA + e0 + ((ng > 1) ? 8 : 0));
            int g = 0;
            while (g + 2 <= ng) {
                // prefetch quads g+2, g+3 (clamped dups on tail, never consumed wrongly)
                uint4 nA = *(const uint4*)(colA + e0 + ((g + 2 < ng) ? (g + 2) * 8 : 0));
                uint4 nB = *(const uint4*)(colA + e0 + ((g + 3 < ng) ? (g + 3) * 8 : 0));
                // 4 row-gathers in flight (16 edges)
                unsigned wAa = qhi ? cwA.y : cwA.x;
                unsigned wAb = qhi ? cwA.w : cwA.z;
                unsigned wBa = qhi ? cwB.y : cwB.x;
                unsigned wBb = qhi ? cwB.w : cwB.z;
                uint4 va = *(const uint4*)(Hs + ((wAa >> shq) & 0xFFFFu) * 64u + ilo);
                uint4 vb = *(const uint4*)(Hs + ((wAb >> shq) & 0xFFFFu) * 64u + ilo);
                uint4 vc = *(const uint4*)(Hs + ((wBa >> shq) & 0xFFFFu) * 64u + ilo);
                uint4 vd = *(const uint4*)(Hs + ((wBb >> shq) & 0xFFFFu) * 64u + ilo);
                a0 += bflo(va.x); a1 += bfhi(va.x);
                a2 += bflo(va.y); a3 += bfhi(va.y);
                a4 += bflo(va.z); a5 += bfhi(va.z);
                a6 += bflo(va.w); a7 += bfhi(va.w);
                c0f += bflo(vb.x); c1f += bfhi(vb.x);
                c2f += bflo(vb.y); c3f += bfhi(vb.y);
                c4f += bflo(vb.z); c5f += bfhi(vb.z);
                c6f += bflo(vb.w); c7f += bfhi(vb.w);
                a0 += bflo(vc.x); a1 += bfhi(vc.x);
                a2 += bflo(vc.y); a3 += bfhi(vc.y);
                a4 += bflo(vc.z); a5 += bfhi(vc.z);
                a6 += bflo(vc.w); a7 += bfhi(vc.w);
                c0f += bflo(vd.x); c1f += bfhi(vd.x);
                c2f += bflo(vd.y); c3f += bfhi(vd.y);
                c4f += bflo(vd.z); c5f += bfhi(vd.z);
                c6f += bflo(vd.w); c7f += bfhi(vd.w);
                cwA = nA; cwB = nB; g += 2;
            }
            if (g < ng) {                     // odd tail group, indices in cwA
                unsigned wAa = qhi ? cwA.y : cwA.x;
                unsigned wAb = qhi ? cwA.w : cwA.z;
                uint4 va = *(const uint4*)(Hs + ((wAa >> shq) & 0xFFFFu) * 64u + ilo);
                uint4 vb = *(const uint4*)(Hs + ((wAb >> shq) & 0xFFFFu) * 64u + ilo);
                a0 += bflo(va.x); a1 += bfhi(va.x);
                a2 += bflo(va.y); a3 += bfhi(va.y);
                a4 += bflo(va.z); a5 += bfhi(va.z);
                a6 += bflo(va.w); a7 += bfhi(va.w);
                c0f += bflo(vb.x); c1f += bfhi(vb.x);
                c2f += bflo(vb.y); c3f += bfhi(vb.y);
                c4f += bflo(vb.z); c5f += bfhi(vb.z);
                c6f += bflo(vb.w); c7f += bfhi(vb.w);
            }
        }
        float s0 = a0 + c0f, s1 = a1 + c1f, s2 = a2 + c2f, s3 = a3 + c3f;
        float s4 = a4 + c4f, s5 = a5 + c5f, s6 = a6 + c6f, s7 = a7 + c7f;

        // prefetch next node (index quad + self row) before the butterfly
        int e0n = e1;
        int e1n = (i < 7) ? __builtin_amdgcn_readfirstlane(__builtin_amdgcn_readlane(rp, i + 2)) : 0;
        int noden = node + 1;
        bool aliven = (i < 7) && (noden < n);
        bool actn = aliven && (e0n < e1n);
        uint4 cwn = {0, 0, 0, 0}, sfn = {0, 0, 0, 0};
        if (aliven) sfn = *(const uint4*)(Hs + (unsigned)noden * 64u + ilo);
        if (actn)   cwn = *(const uint4*)(colA + e0n);

        const int r = wv * 8 + i;
        if (alive) {
            s0 += __shfl_xor(s0, 16); s1 += __shfl_xor(s1, 16);
            s2 += __shfl_xor(s2, 16); s3 += __shfl_xor(s3, 16);
            s4 += __shfl_xor(s4, 16); s5 += __shfl_xor(s5, 16);
            s6 += __shfl_xor(s6, 16); s7 += __shfl_xor(s7, 16);
            s0 += __shfl_xor(s0, 32); s1 += __shfl_xor(s1, 32);
            s2 += __shfl_xor(s2, 32); s3 += __shfl_xor(s3, 32);
            s4 += __shfl_xor(s4, 32); s5 += __shfl_xor(s5, 32);
            s6 += __shfl_xor(s6, 32); s7 += __shfl_xor(s7, 32);
            float di = __uint_as_float((unsigned)__builtin_amdgcn_readlane(dvu, i));
            float o0 = fmaxf((s0 + bflo(sf.x)) * di + bA.x, 0.f);
            float o1 = fmaxf((s1 + bfhi(sf.x)) * di + bA.y, 0.f);
            float o2 = fmaxf((s2 + bflo(sf.y)) * di + bA.z, 0.f);
            float o3 = fmaxf((s3 + bfhi(sf.y)) * di + bA.w, 0.f);
            float o4 = fmaxf((s4 + bflo(sf.z)) * di + bB.x, 0.f);
            float o5 = fmaxf((s5 + bfhi(sf.z)) * di + bB.y, 0.f);
            float o6 = fmaxf((s6 + bflo(sf.w)) * di + bB.z, 0.f);
            float o7 = fmaxf((s7 + bfhi(sf.w)) * di + bB.w, 0.f);
            if (q0) {
                uint4 pk;
                pk.x = (unsigned)f2bf(o0) | ((unsigned)f2bf(o1) << 16);
                pk.y = (unsigned)f2bf(o2) | ((unsigned)f2bf(o3) << 16);
                pk.z = (unsigned)f2bf(o4) | ((unsigned)f2bf(o5) << 16);
                pk.w = (unsigned)f2bf(o6) | ((unsigned)f2bf(o7) << 16);
                *(uint4*)&Ah[r * LSTR + il * 8] = pk;
            }
        } else if (q0) {
            uint4 z = {0, 0, 0, 0};
            *(uint4*)&Ah[r * LSTR + il * 8] = z;
        }
        e0 = e0n; e1 = e1n; cwA = cwn; sf = sfn;
        act = actn; alive = aliven; node = noden;
    }
    __syncthreads();

    const int c0 = wv * 32 + m;                 // all 4 waves: one 32-col block each
    f16v acc = {0.f};
    #pragma unroll
    for (int ks = 0; ks < 8; ++ks) {
        int ko = ks * 16 + half * 8;
        s8v ah = *(const s8v*)&Ah[m * LSTR + ko];
        s8v bh = *(const s8v*)&WTh[(size_t)c0 * 128 + ko];
        s8v bl = *(const s8v*)&WTl[(size_t)c0 * 128 + ko];
        acc = __builtin_amdgcn_mfma_f32_32x32x16_bf16(ah, bh, acc, 0, 0, 0);
        acc = __builtin_amdgcn_mfma_f32_32x32x16_bf16(ah, bl, acc, 0, 0, 0);
    }

    if (FC == 0) {
        #pragma unroll
        for (int reg = 0; reg < 16; ++reg) {
            int rl = (reg & 3) + 8 * (reg >> 2) + 4 * half;
            int gr = row0 + rl;
            if (gr >= n) continue;
            __builtin_nontemporal_store(f2bf(acc[reg] * dinv[gr]),
                                        &oHs[(size_t)gr * 128 + c0]);
        }
    } else {
        short* Pl = SM + 32 * LSTR;
        __syncthreads();                        // all waves done reading Ah
        #pragma unroll
        for (int reg = 0; reg < 16; ++reg) {    // relu(+qq), split into Ah/Pl planes
            int rl = (reg & 3) + 8 * (reg >> 2) + 4 * half;
            int gr = row0 + rl;
            int g = (gr < n) ? batch[gr] : 0;
            float v = fmaxf(acc[reg] + qq[(size_t)g * 128 + c0], 0.f);
            HL p = bsplit(v);
            Ah[rl * LSTR + c0] = p.hi;
            Pl[rl * LSTR + c0] = p.lo;
        }
        __syncthreads();
        f16v acc2 = {0.f};                      // fc2, split-K across the 4 waves
        #pragma unroll
        for (int ks = 0; ks < 2; ++ks) {
            int ko = wv * 32 + ks * 16 + half * 8;
            s8v ah = *(const s8v*)&Ah[m * LSTR + ko];
            s8v al = *(const s8v*)&Pl[m * LSTR + ko];
            s8v bh = *(const s8v*)&W2h[(size_t)m * 128 + ko];
            s8v bl = *(const s8v*)&W2l[(size_t)m * 128 + ko];
            acc2 = __builtin_amdgcn_mfma_f32_32x32x16_bf16(ah, bh, acc2, 0, 0, 0);
            acc2 = __builtin_amdgcn_mfma_f32_32x32x16_bf16(ah, bl, acc2, 0, 0, 0);
            acc2 = __builtin_amdgcn_mfma_f32_32x32x16_bf16(al, bh, acc2, 0, 0, 0);
        }
        __syncthreads();                        // alias guard: Ah/Pl reads all retired
        float* red = (float*)SM;                // 12672 B <= 17408 B (Ah+Pl)
        if (wv > 0) {
            #pragma unroll
            for (int reg = 0; reg < 16; ++reg) {
                int rl = (reg & 3) + 8 * (reg >> 2) + 4 * half;
                red[(wv - 1) * 1056 + rl * 33 + m] = acc2[reg];
            }
        }
        __syncthreads();
        if (wv == 0) {
            #pragma unroll
            for (int reg = 0; reg < 16; ++reg) {
                int rl = (reg & 3) + 8 * (reg >> 2) + 4 * half;
                int gr = row0 + rl;
                if (gr < n) {
                    float v = acc2[reg]
                        + (red[rl * 33 + m] + red[1056 + rl * 33 + m])
                        + red[2112 + rl * 33 + m] + fc2b[m];
                    __builtin_nontemporal_store(v, &out[(size_t)gr * 32 + m]);
                }
            }
        }
    }
}

// ---------------- launch ----------------

extern "C" void kernel_launch(void* const* d_in, const int* in_sizes, int n_in,
                              void* d_out, int out_size, void* d_ws, size_t ws_size,
                              hipStream_t stream) {
    const float* x    = (const float*)d_in[0];
    const int*   ei   = (const int*)d_in[1];
    const int*   batch= (const int*)d_in[2];
    const float* qe   = (const float*)d_in[3];
    const float* W0   = (const float*)d_in[4];
    const float* b0   = (const float*)d_in[5];
    const float* W1   = (const float*)d_in[6];
    const float* b1   = (const float*)d_in[7];
    const float* W2   = (const float*)d_in[8];
    const float* b2   = (const float*)d_in[9];
    const float* fc0w = (const float*)d_in[10];
    const float* fc0b = (const float*)d_in[11];
    const float* fc1w = (const float*)d_in[12];
    const float* fc1b = (const float*)d_in[13];
    const float* fc2w = (const float*)d_in[14];
    const float* fc2b = (const float*)d_in[15];
    float* out = (float*)d_out;

    float* WS = (float*)d_ws;
    unsigned short* HS  = (unsigned short*)WS;                // bf16 [50001,128]
    unsigned short* HS2 = (unsigned short*)(WS + 3200064);    // bf16 [50001,128]
    float* DINV = WS + 6400128;              // [50016]
    float* QQ   = WS + 6450144;              // [8192]
    int*   ROWPTR = (int*)(WS + 6508352);    // [50016]
    int*   RANK = (int*)(WS + 6558368);      // [800000]
    unsigned short* COL = (unsigned short*)(WS + 7358368);    // [1150016] ushort
    int*   BSUM = (int*)(WS + 7933376);      // [128]
    short* WTH  = (short*)(WS + 7933504);    // [69632]
    short* WTL  = WTH + 69632;               // [69632]
    // CNT8/BASE8 overlay HS2's row space (dead until first k_gg writes it)
    int*   CNT8  = (int*)HS2;                // [8][50016]
    int*   BASE8 = CNT8 + 8 * NP;            // [8][50016]

    const int N = N_NODES, E = N_EDGES;
    const int sb = (N + 511) / 512;          // 98
    const int gg = (N + 31) / 32;            // 1563
    const int histb = (E + 511) / 512;       // 1563
    const int fillb = (E + 127) / 128;       // 6250

    // ---- CNT8 zero, then prep (qq + wsplit + colA pad + dummy rows + hist) ----
    (void)hipMemsetAsync(CNT8, 0, 8 * NP * sizeof(int), stream);
    k_prep<<<482 + histb, 512, 0, stream>>>(qe, fc0w, fc0b, fc1w, fc1b,
                                            W0, W1, W2, fc2w, ei, CNT8, RANK,
                                            WTH, WTL, (unsigned*)HS, COL, QQ, E);
    // ---- scan ----
    k_scan_a<<<sb, 512, 0, stream>>>(CNT8, ROWPTR, BSUM, DINV, BASE8, N);
    k_scan_c<<<sb, 512, 0, stream>>>(ROWPTR, BSUM, N, sb);
    // ---- layer-1 GEMM (x@W0 -> HS) + CSR fill (rank replay), merged ----
    k_fg<<<gg + fillb, 128, 0, stream>>>(x, WTH, WTL, DINV, HS,
                                         ei, ROWPTR, RANK, BASE8, COL, N, E, gg);
    // ---- layer 2: gather(HS,b0) + @W1 -> HS2 ----
    k_gg<0><<<gg, 256, 0, stream>>>((const unsigned*)HS, ROWPTR, COL, DINV, b0,
                                    WTH + 16384, WTL + 16384, nullptr, nullptr,
                                    nullptr, nullptr, nullptr, HS2, nullptr, N);
    // ---- layer 3: gather(HS2,b1) + @W2 -> HS ----
    k_gg<0><<<gg, 256, 0, stream>>>((const unsigned*)HS2, ROWPTR, COL, DINV, b1,
                                    WTH + 32768, WTL + 32768, nullptr, nullptr,
                                    nullptr, nullptr, nullptr, HS, nullptr, N);
    // ---- final: gather(HS,b2) + fc1(+qq,relu) + fc2 -> d_out ----
    k_gg<1><<<gg, 256, 0, stream>>>((const unsigned*)HS, ROWPTR, COL, DINV, b2,
                                    WTH + 49152, WTL + 49152, WTH + 65536, WTL + 65536,
                                    QQ, batch, fc2b, nullptr, out, N);
}